// Round 8
// baseline (562.864 us; speedup 1.0000x reference)
//
#include <hip/hip_runtime.h>
#include <hip/hip_bf16.h>
#include <math.h>
#include <stdint.h>

#define N_NODES 40000
#define N_EDGES 640000

typedef short short8 __attribute__((ext_vector_type(8)));
typedef float f32x4 __attribute__((ext_vector_type(4)));

// fast silu: v_exp + v_rcp path (no slow IEEE divide sequence)
__device__ __forceinline__ float silu(float x) {
    return __fdividef(x, 1.0f + __expf(-x));
}

__device__ __forceinline__ unsigned short f2bf(float f) {
    unsigned u = __float_as_uint(f);
    u += 0x7FFF + ((u >> 16) & 1);            // round-to-nearest-even
    return (unsigned short)(u >> 16);
}
__device__ __forceinline__ float bf2f(unsigned short h) {
    return __uint_as_float(((unsigned)h) << 16);
}
// packed pair conversion -> v_cvt_pk_bf16_f32 on gfx950 (lo=a, hi=b)
__device__ __forceinline__ unsigned pk2bf(float a, float b) {
    __hip_bfloat162 h = __float22bfloat162_rn(make_float2(a, b));
    unsigned u;
    __builtin_memcpy(&u, &h, 4);
    return u;
}

// ---------------------------------------------------------------------------
// CSR build: deg histogram -> exclusive scan -> fill permuted edge list.
// ---------------------------------------------------------------------------
__global__ __launch_bounds__(256) void k_count(const int* __restrict__ dst,
                                               int* __restrict__ deg) {
    const int e = blockIdx.x * 256 + threadIdx.x;
    if (e < N_EDGES) atomicAdd(&deg[dst[e]], 1);
}

// Shuffle-based hierarchical scan: 3 barriers/chunk.
__global__ __launch_bounds__(1024) void k_scan(const int* __restrict__ deg,
                                               int* __restrict__ row_start) {
    __shared__ int wsum[16];
    const int t = threadIdx.x;
    const int lane = t & 63, wid = t >> 6;
    int base = 0;
    if (t == 0) row_start[0] = 0;
    for (int off = 0; off < N_NODES; off += 1024) {
        int x = (off + t < N_NODES) ? deg[off + t] : 0;
#pragma unroll
        for (int s = 1; s < 64; s <<= 1) {
            const int u = __shfl_up(x, s, 64);
            if (lane >= s) x += u;
        }
        if (lane == 63) wsum[wid] = x;
        __syncthreads();
        if (wid == 0) {
            int ws = (lane < 16) ? wsum[lane] : 0;
#pragma unroll
            for (int s = 1; s < 16; s <<= 1) {
                const int u = __shfl_up(ws, s, 64);
                if (lane >= s) ws += u;
            }
            if (lane < 16) wsum[lane] = ws;
        }
        __syncthreads();
        const int wbase = (wid > 0) ? wsum[wid - 1] : 0;
        const int total = wsum[15];
        if (off + t < N_NODES) row_start[off + t + 1] = base + wbase + x;
        base += total;
        __syncthreads();
    }
}

__global__ __launch_bounds__(256) void k_fill(const int* __restrict__ dst,
                                              const int* __restrict__ row_start,
                                              int* __restrict__ cursor,
                                              int* __restrict__ elist) {
    const int e = blockIdx.x * 256 + threadIdx.x;
    if (e < N_EDGES) {
        const int d = dst[e];
        const int p = atomicAdd(&cursor[d], 1);
        elist[row_start[d] + p] = e;
    }
}

// ---------------------------------------------------------------------------
// k_pack2: bf16-transposed weight packs Wt[n][k] = bf16(W[k][n]); also zeroes
// deg/cursor/xs/hn (folded memsets; stream order covers the later consumers).
// ---------------------------------------------------------------------------
__global__ __launch_bounds__(128) void k_pack2(
    const float* __restrict__ We1, const float* __restrict__ We2,
    const float* __restrict__ Wc1, const float* __restrict__ Wn1,
    const float* __restrict__ Wn2,
    unsigned short* __restrict__ Wt_e1, unsigned short* __restrict__ Wt_e2,
    unsigned short* __restrict__ Wt_c1, unsigned short* __restrict__ Wt_n1,
    unsigned short* __restrict__ Wt_n2,
    int* __restrict__ deg, int* __restrict__ cursor, float* __restrict__ xs,
    float* __restrict__ hn) {
    const int b = blockIdx.x;   // 0..255
    const int t = threadIdx.x;  // 0..127
    Wt_e1[b * 128 + t] = f2bf(We1[(size_t)((b >> 7) * 128 + t) * 128 + (b & 127)]);
    if (b < 128) {
        Wt_e2[b * 128 + t] = f2bf(We2[(size_t)t * 128 + b]);
        Wt_c1[b * 128 + t] = f2bf(Wc1[(size_t)t * 128 + b]);
        Wt_n2[b * 128 + t] = f2bf(Wn2[(size_t)t * 128 + b]);
        Wt_n1[b * 256 + t] = f2bf(Wn1[(size_t)t * 128 + b]);
        Wt_n1[b * 256 + 128 + t] = f2bf(Wn1[(size_t)(128 + t) * 128 + b]);
    }
    const int gid = b * 128 + t;                   // 0..32767
    for (int i = gid; i < N_NODES; i += 32768) { deg[i] = 0; cursor[i] = 0; }
    for (int i = gid; i < N_NODES * 4; i += 32768) xs[i] = 0.0f;
    float4* hz = (float4*)hn;                      // N*128 f32 = N*32 float4
    const float4 z4 = {0.f, 0.f, 0.f, 0.f};
    for (int i = gid; i < N_NODES * 32; i += 32768) hz[i] = z4;
}

// ---------------------------------------------------------------------------
// k_pre (MFMA): Pc[node][0:128]=nf@We1a, Pc[node][128:256]=nf@We1b, bf16 out.
// ---------------------------------------------------------------------------
__global__ __launch_bounds__(256) void k_pre(
    const float* __restrict__ nf, const unsigned short* __restrict__ Wt_e1,
    unsigned short* __restrict__ Pc) {
    __shared__ __align__(16) unsigned short sNF[32][136];
    const int t = threadIdx.x;
    const int node0 = blockIdx.x * 32;
    {
        const int m = t >> 3, kc = (t & 7) * 16;
        const float* sp = &nf[(size_t)(node0 + m) * 128 + kc];
        const float4 v0 = *(const float4*)(sp + 0);
        const float4 v1 = *(const float4*)(sp + 4);
        const float4 v2 = *(const float4*)(sp + 8);
        const float4 v3 = *(const float4*)(sp + 12);
        int4 o0, o1;
        o0.x = pk2bf(v0.x, v0.y); o0.y = pk2bf(v0.z, v0.w);
        o0.z = pk2bf(v1.x, v1.y); o0.w = pk2bf(v1.z, v1.w);
        o1.x = pk2bf(v2.x, v2.y); o1.y = pk2bf(v2.z, v2.w);
        o1.z = pk2bf(v3.x, v3.y); o1.w = pk2bf(v3.z, v3.w);
        *(int4*)&sNF[m][kc] = o0;
        *(int4*)&sNF[m][kc + 8] = o1;
    }
    __syncthreads();

    const int w = t >> 6, l = t & 63, c = l & 15, quad = l >> 4;
    const int n0 = w * 64;

    f32x4 acc[2][4];
#pragma unroll
    for (int mt = 0; mt < 2; mt++)
#pragma unroll
        for (int tile = 0; tile < 4; tile++) acc[mt][tile] = (f32x4){0.f, 0.f, 0.f, 0.f};

#pragma unroll
    for (int k0 = 0; k0 < 128; k0 += 32) {
        const short8 a0 = *(const short8*)&sNF[c][k0 + quad * 8];
        const short8 a1 = *(const short8*)&sNF[16 + c][k0 + quad * 8];
#pragma unroll
        for (int tile = 0; tile < 4; tile++) {
            const short8 b = *(const short8*)(Wt_e1 +
                ((size_t)(n0 + tile * 16 + c) << 7) + k0 + quad * 8);
            acc[0][tile] = __builtin_amdgcn_mfma_f32_16x16x32_bf16(a0, b, acc[0][tile], 0, 0, 0);
            acc[1][tile] = __builtin_amdgcn_mfma_f32_16x16x32_bf16(a1, b, acc[1][tile], 0, 0, 0);
        }
    }
#pragma unroll
    for (int mt = 0; mt < 2; mt++)
#pragma unroll
        for (int tile = 0; tile < 4; tile++) {
            const int col = n0 + tile * 16 + c;
            const unsigned p01 = pk2bf(acc[mt][tile][0], acc[mt][tile][1]);
            const unsigned p23 = pk2bf(acc[mt][tile][2], acc[mt][tile][3]);
            const int row = node0 + mt * 16 + quad * 4;
            Pc[(size_t)(row + 0) * 256 + col] = (unsigned short)p01;
            Pc[(size_t)(row + 1) * 256 + col] = (unsigned short)(p01 >> 16);
            Pc[(size_t)(row + 2) * 256 + col] = (unsigned short)p23;
            Pc[(size_t)(row + 3) * 256 + col] = (unsigned short)(p23 >> 16);
        }
}

// ---------------------------------------------------------------------------
// k_edge4: 64 CSR-permuted edges per 512-thread block (8 waves).
//   wave w: edge quarter h=w&3 (m0=h*16), col half H=w>>2 (n0=H*64).
//   h-scatter issued BEFORE GEMM2 so atomics drain under MFMA work.
// ---------------------------------------------------------------------------
__global__ __launch_bounds__(512) void k_edge4(
    const unsigned short* __restrict__ Pc, const float* __restrict__ coord,
    const int* __restrict__ src, const int* __restrict__ dst,
    const int* __restrict__ elist,
    const float* __restrict__ We1, const float* __restrict__ be1,
    const unsigned short* __restrict__ Wt_e2, const float* __restrict__ be2,
    const unsigned short* __restrict__ Wt_c1, const float* __restrict__ bc1,
    const float* __restrict__ Wc2,
    float* __restrict__ h_neigh, float* __restrict__ xs) {
    __shared__ __align__(16) unsigned short sT1[64][136];
    __shared__ __align__(16) unsigned short sT2[64][136];
    __shared__ float scoefp[8][16];
    __shared__ float sw[128], sb[128];
    __shared__ float sdist[64];
    __shared__ float sxd[64][3];
    __shared__ int ssrc[64];
    __shared__ int sdst[64];

    const int t = threadIdx.x;
    const int e0 = blockIdx.x * 64;

    if (t < 64) {
        const int eid = elist[e0 + t];
        const int s = src[eid], d = dst[eid];
        ssrc[t] = s; sdst[t] = d;
        const float dx = coord[3 * s + 0] - coord[3 * d + 0];
        const float dy = coord[3 * s + 1] - coord[3 * d + 1];
        const float dz = coord[3 * s + 2] - coord[3 * d + 2];
        const float dist = sqrtf(dx * dx + dy * dy + dz * dz);
        sdist[t] = dist;
        const float inv = __fdividef(1.0f, dist + 1e-7f);
        sxd[t][0] = dx * inv; sxd[t][1] = dy * inv; sxd[t][2] = dz * inv;
    } else if (t < 96) {
        ((float4*)sw)[t - 64] = ((const float4*)(We1 + 256 * 128))[t - 64];
    } else if (t < 128) {
        ((float4*)sb)[t - 96] = ((const float4*)be1)[t - 96];
    }
    __syncthreads();

    // t1 = silu(P1[s] + P2[d] + dist*We1[256] + be1), bf16, packed cvt + b128
    {
        const int e = t >> 3;
        const int kc = (t & 7) * 16;
        const int s = ssrc[e], d = sdst[e];
        const float dist = sdist[e];
        const unsigned short* p1 = Pc + (size_t)s * 256 + kc;
        const unsigned short* p2 = Pc + (size_t)d * 256 + 128 + kc;
        const short8 a0 = *(const short8*)p1;
        const short8 a1 = *(const short8*)(p1 + 8);
        const short8 b0 = *(const short8*)p2;
        const short8 b1 = *(const short8*)(p2 + 8);
        float v[16];
#pragma unroll
        for (int kk = 0; kk < 8; kk++) {
            v[kk] = silu(bf2f((unsigned short)a0[kk]) + bf2f((unsigned short)b0[kk])
                         + dist * sw[kc + kk] + sb[kc + kk]);
        }
#pragma unroll
        for (int kk = 0; kk < 8; kk++) {
            v[8 + kk] = silu(bf2f((unsigned short)a1[kk]) + bf2f((unsigned short)b1[kk])
                             + dist * sw[kc + 8 + kk] + sb[kc + 8 + kk]);
        }
        int4 o0, o1;
        o0.x = pk2bf(v[0], v[1]);  o0.y = pk2bf(v[2], v[3]);
        o0.z = pk2bf(v[4], v[5]);  o0.w = pk2bf(v[6], v[7]);
        o1.x = pk2bf(v[8], v[9]);  o1.y = pk2bf(v[10], v[11]);
        o1.z = pk2bf(v[12], v[13]); o1.w = pk2bf(v[14], v[15]);
        *(int4*)&sT1[e][kc] = o0;
        *(int4*)&sT1[e][kc + 8] = o1;
    }
    __syncthreads();

    const int w = t >> 6;
    const int l = t & 63;
    const int h = w & 3;      // edge quarter
    const int H = w >> 2;     // col half
    const int m0 = h * 16;
    const int n0 = H * 64;
    const int c = l & 15;
    const int quad = l >> 4;

    // ---- GEMM1: t2 = silu(t1 @ We2 + be2) ----
    {
        f32x4 acc[4];
#pragma unroll
        for (int tile = 0; tile < 4; tile++) acc[tile] = (f32x4){0.f, 0.f, 0.f, 0.f};
#pragma unroll
        for (int k0 = 0; k0 < 128; k0 += 32) {
            const short8 a = *(const short8*)&sT1[m0 + c][k0 + quad * 8];
#pragma unroll
            for (int tile = 0; tile < 4; tile++) {
                const short8 b = *(const short8*)(Wt_e2 +
                    ((size_t)(n0 + tile * 16 + c) << 7) + k0 + quad * 8);
                acc[tile] = __builtin_amdgcn_mfma_f32_16x16x32_bf16(a, b, acc[tile], 0, 0, 0);
            }
        }
#pragma unroll
        for (int tile = 0; tile < 4; tile++) {
            const int col = n0 + tile * 16 + c;
            const float bb = be2[col];
            const unsigned p01 = pk2bf(silu(acc[tile][0] + bb), silu(acc[tile][1] + bb));
            const unsigned p23 = pk2bf(silu(acc[tile][2] + bb), silu(acc[tile][3] + bb));
            const int row = m0 + quad * 4;
            sT2[row + 0][col] = (unsigned short)p01;
            sT2[row + 1][col] = (unsigned short)(p01 >> 16);
            sT2[row + 2][col] = (unsigned short)p23;
            sT2[row + 3][col] = (unsigned short)(p23 >> 16);
        }
    }
    __syncthreads();

    // ---- h-scatter first: atomics drain under GEMM2's compute ----
    {
        const int j = t & 127;
        const int q = t >> 7;
        const int eb = q * 16;
        float acc = bf2f(sT2[eb][j]);
        int prev = sdst[eb];
        for (int e2 = eb + 1; e2 < eb + 16; e2++) {
            const int de = sdst[e2];
            if (de != prev) {
                atomicAdd(&h_neigh[(size_t)prev * 128 + j], acc);
                acc = 0.0f;
                prev = de;
            }
            acc += bf2f(sT2[e2][j]);
        }
        atomicAdd(&h_neigh[(size_t)prev * 128 + j], acc);
    }

    // ---- GEMM2: coef = silu(t2 @ Wc1 + bc1) . Wc2 ----
    {
        f32x4 acc[4];
#pragma unroll
        for (int tile = 0; tile < 4; tile++) acc[tile] = (f32x4){0.f, 0.f, 0.f, 0.f};
#pragma unroll
        for (int k0 = 0; k0 < 128; k0 += 32) {
            const short8 a = *(const short8*)&sT2[m0 + c][k0 + quad * 8];
#pragma unroll
            for (int tile = 0; tile < 4; tile++) {
                const short8 b = *(const short8*)(Wt_c1 +
                    ((size_t)(n0 + tile * 16 + c) << 7) + k0 + quad * 8);
                acc[tile] = __builtin_amdgcn_mfma_f32_16x16x32_bf16(a, b, acc[tile], 0, 0, 0);
            }
        }
        float part[4] = {0.f, 0.f, 0.f, 0.f};
#pragma unroll
        for (int tile = 0; tile < 4; tile++) {
            const int col = n0 + tile * 16 + c;
            const float bc = bc1[col];
            const float wc = Wc2[col];
#pragma unroll
            for (int r = 0; r < 4; r++) part[r] += silu(acc[tile][r] + bc) * wc;
        }
#pragma unroll
        for (int off = 1; off < 16; off <<= 1) {
#pragma unroll
            for (int r = 0; r < 4; r++) part[r] += __shfl_xor(part[r], off, 64);
        }
        if (c == 0) {
#pragma unroll
            for (int r = 0; r < 4; r++) scoefp[w][quad * 4 + r] = part[r];
        }
    }
    __syncthreads();

    // ---- x-scatter (12 threads; coef = colhalf0 + colhalf1 partials) ----
    if (t < 12) {
        const int q = t / 3, cc = t - q * 3;
        const int eb = q * 16;
        float coef = scoefp[eb >> 4][eb & 15] + scoefp[(eb >> 4) + 4][eb & 15];
        float acc = coef * sxd[eb][cc];
        int prev = sdst[eb];
        for (int e2 = eb + 1; e2 < eb + 16; e2++) {
            const int de = sdst[e2];
            if (de != prev) {
                atomicAdd(&xs[(size_t)prev * 4 + cc], acc);
                acc = 0.0f;
                prev = de;
            }
            coef = scoefp[e2 >> 4][e2 & 15] + scoefp[(e2 >> 4) + 4][e2 & 15];
            acc += coef * sxd[e2][cc];
        }
        atomicAdd(&xs[(size_t)prev * 4 + cc], acc);
    }
}

// ---------------------------------------------------------------------------
// k_node (MFMA): h = silu([nf|hn] @ Wn1 + bn1) @ Wn2 + bn2 ; x = coord+xs/cnt
// ---------------------------------------------------------------------------
__global__ __launch_bounds__(256) void k_node(
    const float* __restrict__ nf, const float* __restrict__ coord,
    const float* __restrict__ hn, const float* __restrict__ xs,
    const int* __restrict__ row_start,
    const unsigned short* __restrict__ Wt_n1, const float* __restrict__ bn1,
    const unsigned short* __restrict__ Wt_n2, const float* __restrict__ bn2,
    float* __restrict__ out_h, float* __restrict__ out_x) {
    __shared__ __align__(16) unsigned short sAB[32][264];
    __shared__ __align__(16) unsigned short sH[32][136];
    const int t = threadIdx.x;
    const int node0 = blockIdx.x * 32;
    {
        const int m = t >> 3, kc = (t & 7) * 32;
        const float* base = (kc < 128) ? &nf[(size_t)(node0 + m) * 128 + kc]
                                       : &hn[(size_t)(node0 + m) * 128 + (kc - 128)];
#pragma unroll
        for (int kk = 0; kk < 32; kk += 8) {
            const float4 v0 = *(const float4*)(base + kk);
            const float4 v1 = *(const float4*)(base + kk + 4);
            int4 o;
            o.x = pk2bf(v0.x, v0.y); o.y = pk2bf(v0.z, v0.w);
            o.z = pk2bf(v1.x, v1.y); o.w = pk2bf(v1.z, v1.w);
            *(int4*)&sAB[m][kc + kk] = o;
        }
    }
    if (t < 96) {
        const int m = t / 3, cc = t - m * 3;
        const int i = node0 + m;
        const float cnt = (float)(row_start[i + 1] - row_start[i]);
        out_x[(size_t)i * 3 + cc] =
            coord[(size_t)i * 3 + cc] + __fdividef(xs[(size_t)i * 4 + cc], fmaxf(cnt, 1.0f));
    }
    __syncthreads();

    const int w = t >> 6, l = t & 63, c = l & 15, quad = l >> 4;
    const int n0 = w * 32;

    // GEMM1: M=32, K=256, N=128
    {
        f32x4 acc[2][2];
#pragma unroll
        for (int mt = 0; mt < 2; mt++)
#pragma unroll
            for (int tile = 0; tile < 2; tile++) acc[mt][tile] = (f32x4){0.f, 0.f, 0.f, 0.f};
#pragma unroll
        for (int k0 = 0; k0 < 256; k0 += 32) {
            const short8 a0 = *(const short8*)&sAB[c][k0 + quad * 8];
            const short8 a1 = *(const short8*)&sAB[16 + c][k0 + quad * 8];
#pragma unroll
            for (int tile = 0; tile < 2; tile++) {
                const short8 b = *(const short8*)(Wt_n1 +
                    ((size_t)(n0 + tile * 16 + c) << 8) + k0 + quad * 8);
                acc[0][tile] = __builtin_amdgcn_mfma_f32_16x16x32_bf16(a0, b, acc[0][tile], 0, 0, 0);
                acc[1][tile] = __builtin_amdgcn_mfma_f32_16x16x32_bf16(a1, b, acc[1][tile], 0, 0, 0);
            }
        }
#pragma unroll
        for (int mt = 0; mt < 2; mt++)
#pragma unroll
            for (int tile = 0; tile < 2; tile++) {
                const int col = n0 + tile * 16 + c;
                const float bb = bn1[col];
                const unsigned p01 = pk2bf(silu(acc[mt][tile][0] + bb), silu(acc[mt][tile][1] + bb));
                const unsigned p23 = pk2bf(silu(acc[mt][tile][2] + bb), silu(acc[mt][tile][3] + bb));
                const int row = mt * 16 + quad * 4;
                sH[row + 0][col] = (unsigned short)p01;
                sH[row + 1][col] = (unsigned short)(p01 >> 16);
                sH[row + 2][col] = (unsigned short)p23;
                sH[row + 3][col] = (unsigned short)(p23 >> 16);
            }
    }
    __syncthreads();

    // GEMM2: M=32, K=128, N=128
    {
        f32x4 acc[2][2];
#pragma unroll
        for (int mt = 0; mt < 2; mt++)
#pragma unroll
            for (int tile = 0; tile < 2; tile++) acc[mt][tile] = (f32x4){0.f, 0.f, 0.f, 0.f};
#pragma unroll
        for (int k0 = 0; k0 < 128; k0 += 32) {
            const short8 a0 = *(const short8*)&sH[c][k0 + quad * 8];
            const short8 a1 = *(const short8*)&sH[16 + c][k0 + quad * 8];
#pragma unroll
            for (int tile = 0; tile < 2; tile++) {
                const short8 b = *(const short8*)(Wt_n2 +
                    ((size_t)(n0 + tile * 16 + c) << 7) + k0 + quad * 8);
                acc[0][tile] = __builtin_amdgcn_mfma_f32_16x16x32_bf16(a0, b, acc[0][tile], 0, 0, 0);
                acc[1][tile] = __builtin_amdgcn_mfma_f32_16x16x32_bf16(a1, b, acc[1][tile], 0, 0, 0);
            }
        }
#pragma unroll
        for (int mt = 0; mt < 2; mt++)
#pragma unroll
            for (int tile = 0; tile < 2; tile++) {
                const int col = n0 + tile * 16 + c;
                const float bb = bn2[col];
#pragma unroll
                for (int r = 0; r < 4; r++) {
                    const int row = mt * 16 + quad * 4 + r;
                    out_h[(size_t)(node0 + row) * 128 + col] = acc[mt][tile][r] + bb;
                }
            }
    }
}

// ---------------------------------------------------------------------------
extern "C" void kernel_launch(void* const* d_in, const int* in_sizes, int n_in,
                              void* d_out, int out_size, void* d_ws, size_t ws_size,
                              hipStream_t stream) {
    const float* nf    = (const float*)d_in[0];
    const float* coord = (const float*)d_in[1];
    const int*   src   = (const int*)d_in[2];
    const int*   dst   = (const int*)d_in[3];
    const float* We1   = (const float*)d_in[4];
    const float* be1   = (const float*)d_in[5];
    const float* We2   = (const float*)d_in[6];
    const float* be2   = (const float*)d_in[7];
    const float* Wn1   = (const float*)d_in[8];
    const float* bn1   = (const float*)d_in[9];
    const float* Wn2   = (const float*)d_in[10];
    const float* bn2   = (const float*)d_in[11];
    const float* Wc1   = (const float*)d_in[12];
    const float* bc1   = (const float*)d_in[13];
    const float* Wc2   = (const float*)d_in[14];

    unsigned short* Pc = (unsigned short*)d_ws;            // N*256 bf16
    float* hn = (float*)(Pc + (size_t)N_NODES * 256);      // N*128 f32
    float* xs = hn + (size_t)N_NODES * 128;                // N*4
    int* deg       = (int*)(xs + (size_t)N_NODES * 4);     // N
    int* row_start = deg + N_NODES;                        // N+1
    int* cursor    = row_start + N_NODES + 1;              // N
    int* elist     = cursor + N_NODES;                     // E
    unsigned short* Wt_e1 = (unsigned short*)
        (((uintptr_t)(elist + N_EDGES) + 255) & ~(uintptr_t)255);  // 256*128
    unsigned short* Wt_e2 = Wt_e1 + 256 * 128;                     // 128*128
    unsigned short* Wt_c1 = Wt_e2 + 128 * 128;                     // 128*128
    unsigned short* Wt_n1 = Wt_c1 + 128 * 128;                     // 128*256
    unsigned short* Wt_n2 = Wt_n1 + 128 * 256;                     // 128*128

    float* out_h = (float*)d_out;                          // N*128
    float* out_x = out_h + (size_t)N_NODES * 128;          // N*3

    k_pack2<<<256, 128, 0, stream>>>(We1, We2, Wc1, Wn1, Wn2,
                                     Wt_e1, Wt_e2, Wt_c1, Wt_n1, Wt_n2,
                                     deg, cursor, xs, hn);
    k_count<<<(N_EDGES + 255) / 256, 256, 0, stream>>>(dst, deg);
    k_scan<<<1, 1024, 0, stream>>>(deg, row_start);
    k_fill<<<(N_EDGES + 255) / 256, 256, 0, stream>>>(dst, row_start, cursor, elist);
    k_pre<<<N_NODES / 32, 256, 0, stream>>>(nf, Wt_e1, Pc);
    k_edge4<<<N_EDGES / 64, 512, 0, stream>>>(Pc, coord, src, dst, elist,
                                              We1, be1, Wt_e2, be2, Wt_c1, bc1,
                                              Wc2, hn, xs);
    k_node<<<N_NODES / 32, 256, 0, stream>>>(nf, coord, hn, xs, row_start,
                                             Wt_n1, bn1, Wt_n2, bn2, out_h, out_x);
}

// Round 9
// 495.973 us; speedup vs baseline: 1.1349x; 1.1349x over previous
//
#include <hip/hip_runtime.h>
#include <hip/hip_bf16.h>
#include <math.h>
#include <stdint.h>

#define N_NODES 40000
#define N_EDGES 640000

typedef short short8 __attribute__((ext_vector_type(8)));
typedef float f32x4 __attribute__((ext_vector_type(4)));

__device__ __forceinline__ float silu(float x) {
    return __fdividef(x, 1.0f + __expf(-x));
}

__device__ __forceinline__ unsigned short f2bf(float f) {
    unsigned u = __float_as_uint(f);
    u += 0x7FFF + ((u >> 16) & 1);
    return (unsigned short)(u >> 16);
}
__device__ __forceinline__ float bf2f(unsigned short h) {
    return __uint_as_float(((unsigned)h) << 16);
}
__device__ __forceinline__ unsigned pk2bf(float a, float b) {
    __hip_bfloat162 h = __float22bfloat162_rn(make_float2(a, b));
    unsigned u;
    __builtin_memcpy(&u, &h, 4);
    return u;
}

// ---------------------------------------------------------------------------
// CSR build: deg histogram -> exclusive scan -> fill permuted edge list.
// ---------------------------------------------------------------------------
__global__ __launch_bounds__(256) void k_count(const int* __restrict__ dst,
                                               int* __restrict__ deg) {
    const int e = blockIdx.x * 256 + threadIdx.x;
    if (e < N_EDGES) atomicAdd(&deg[dst[e]], 1);
}

__global__ __launch_bounds__(1024) void k_scan(const int* __restrict__ deg,
                                               int* __restrict__ row_start) {
    __shared__ int wsum[16];
    const int t = threadIdx.x;
    const int lane = t & 63, wid = t >> 6;
    int base = 0;
    if (t == 0) row_start[0] = 0;
    for (int off = 0; off < N_NODES; off += 1024) {
        int x = (off + t < N_NODES) ? deg[off + t] : 0;
#pragma unroll
        for (int s = 1; s < 64; s <<= 1) {
            const int u = __shfl_up(x, s, 64);
            if (lane >= s) x += u;
        }
        if (lane == 63) wsum[wid] = x;
        __syncthreads();
        if (wid == 0) {
            int ws = (lane < 16) ? wsum[lane] : 0;
#pragma unroll
            for (int s = 1; s < 16; s <<= 1) {
                const int u = __shfl_up(ws, s, 64);
                if (lane >= s) ws += u;
            }
            if (lane < 16) wsum[lane] = ws;
        }
        __syncthreads();
        const int wbase = (wid > 0) ? wsum[wid - 1] : 0;
        const int total = wsum[15];
        if (off + t < N_NODES) row_start[off + t + 1] = base + wbase + x;
        base += total;
        __syncthreads();
    }
}

__global__ __launch_bounds__(256) void k_fill(const int* __restrict__ dst,
                                              const int* __restrict__ row_start,
                                              int* __restrict__ cursor,
                                              int* __restrict__ elist) {
    const int e = blockIdx.x * 256 + threadIdx.x;
    if (e < N_EDGES) {
        const int d = dst[e];
        const int p = atomicAdd(&cursor[d], 1);
        elist[row_start[d] + p] = e;
    }
}

// ---------------------------------------------------------------------------
// k_pack2: bf16-transposed weight packs + folded memsets (deg/cursor/xs/hn).
// ---------------------------------------------------------------------------
__global__ __launch_bounds__(128) void k_pack2(
    const float* __restrict__ We1, const float* __restrict__ We2,
    const float* __restrict__ Wc1, const float* __restrict__ Wn1,
    const float* __restrict__ Wn2,
    unsigned short* __restrict__ Wt_e1, unsigned short* __restrict__ Wt_e2,
    unsigned short* __restrict__ Wt_c1, unsigned short* __restrict__ Wt_n1,
    unsigned short* __restrict__ Wt_n2,
    int* __restrict__ deg, int* __restrict__ cursor, float* __restrict__ xs,
    float* __restrict__ hn) {
    const int b = blockIdx.x;   // 0..255
    const int t = threadIdx.x;  // 0..127
    Wt_e1[b * 128 + t] = f2bf(We1[(size_t)((b >> 7) * 128 + t) * 128 + (b & 127)]);
    if (b < 128) {
        Wt_e2[b * 128 + t] = f2bf(We2[(size_t)t * 128 + b]);
        Wt_c1[b * 128 + t] = f2bf(Wc1[(size_t)t * 128 + b]);
        Wt_n2[b * 128 + t] = f2bf(Wn2[(size_t)t * 128 + b]);
        Wt_n1[b * 256 + t] = f2bf(Wn1[(size_t)t * 128 + b]);
        Wt_n1[b * 256 + 128 + t] = f2bf(Wn1[(size_t)(128 + t) * 128 + b]);
    }
    const int gid = b * 128 + t;                   // 0..32767
    for (int i = gid; i < N_NODES; i += 32768) { deg[i] = 0; cursor[i] = 0; }
    for (int i = gid; i < N_NODES * 4; i += 32768) xs[i] = 0.0f;
    float4* hz = (float4*)hn;
    const float4 z4 = {0.f, 0.f, 0.f, 0.f};
    for (int i = gid; i < N_NODES * 32; i += 32768) hz[i] = z4;
}

// ---------------------------------------------------------------------------
// k_pre (MFMA): Pc[node][0:128]=nf@We1a, Pc[node][128:256]=nf@We1b, bf16 out.
// ---------------------------------------------------------------------------
__global__ __launch_bounds__(256) void k_pre(
    const float* __restrict__ nf, const unsigned short* __restrict__ Wt_e1,
    unsigned short* __restrict__ Pc) {
    __shared__ __align__(16) unsigned short sNF[32][136];
    const int t = threadIdx.x;
    const int node0 = blockIdx.x * 32;
    {
        const int m = t >> 3, kc = (t & 7) * 16;
        const float* sp = &nf[(size_t)(node0 + m) * 128 + kc];
        const float4 v0 = *(const float4*)(sp + 0);
        const float4 v1 = *(const float4*)(sp + 4);
        const float4 v2 = *(const float4*)(sp + 8);
        const float4 v3 = *(const float4*)(sp + 12);
        int4 o0, o1;
        o0.x = pk2bf(v0.x, v0.y); o0.y = pk2bf(v0.z, v0.w);
        o0.z = pk2bf(v1.x, v1.y); o0.w = pk2bf(v1.z, v1.w);
        o1.x = pk2bf(v2.x, v2.y); o1.y = pk2bf(v2.z, v2.w);
        o1.z = pk2bf(v3.x, v3.y); o1.w = pk2bf(v3.z, v3.w);
        *(int4*)&sNF[m][kc] = o0;
        *(int4*)&sNF[m][kc + 8] = o1;
    }
    __syncthreads();

    const int w = t >> 6, l = t & 63, c = l & 15, quad = l >> 4;
    const int n0 = w * 64;

    f32x4 acc[2][4];
#pragma unroll
    for (int mt = 0; mt < 2; mt++)
#pragma unroll
        for (int tile = 0; tile < 4; tile++) acc[mt][tile] = (f32x4){0.f, 0.f, 0.f, 0.f};

#pragma unroll
    for (int k0 = 0; k0 < 128; k0 += 32) {
        const short8 a0 = *(const short8*)&sNF[c][k0 + quad * 8];
        const short8 a1 = *(const short8*)&sNF[16 + c][k0 + quad * 8];
#pragma unroll
        for (int tile = 0; tile < 4; tile++) {
            const short8 b = *(const short8*)(Wt_e1 +
                ((size_t)(n0 + tile * 16 + c) << 7) + k0 + quad * 8);
            acc[0][tile] = __builtin_amdgcn_mfma_f32_16x16x32_bf16(a0, b, acc[0][tile], 0, 0, 0);
            acc[1][tile] = __builtin_amdgcn_mfma_f32_16x16x32_bf16(a1, b, acc[1][tile], 0, 0, 0);
        }
    }
#pragma unroll
    for (int mt = 0; mt < 2; mt++)
#pragma unroll
        for (int tile = 0; tile < 4; tile++) {
            const int col = n0 + tile * 16 + c;
            const unsigned p01 = pk2bf(acc[mt][tile][0], acc[mt][tile][1]);
            const unsigned p23 = pk2bf(acc[mt][tile][2], acc[mt][tile][3]);
            const int row = node0 + mt * 16 + quad * 4;
            Pc[(size_t)(row + 0) * 256 + col] = (unsigned short)p01;
            Pc[(size_t)(row + 1) * 256 + col] = (unsigned short)(p01 >> 16);
            Pc[(size_t)(row + 2) * 256 + col] = (unsigned short)p23;
            Pc[(size_t)(row + 3) * 256 + col] = (unsigned short)(p23 >> 16);
        }
}

// ---------------------------------------------------------------------------
// k_edge5: 128 CSR-permuted edges per 512-thread block (8 waves).
//   Single LDS tile sT reused: t1 (GEMM1 input) then t2 (in-place overwrite
//   after a barrier — GEMM1 accs live in registers). wave w: edge block
//   h=w&3 (32 edges, m0=h*32, 2 m-tiles), col half H=w>>2 (n0=H*64).
// ---------------------------------------------------------------------------
__global__ __launch_bounds__(512) void k_edge5(
    const unsigned short* __restrict__ Pc, const float* __restrict__ coord,
    const int* __restrict__ src, const int* __restrict__ dst,
    const int* __restrict__ elist,
    const float* __restrict__ We1, const float* __restrict__ be1,
    const unsigned short* __restrict__ Wt_e2, const float* __restrict__ be2,
    const unsigned short* __restrict__ Wt_c1, const float* __restrict__ bc1,
    const float* __restrict__ Wc2,
    float* __restrict__ h_neigh, float* __restrict__ xs) {
    __shared__ __align__(16) unsigned short sT[128][136];
    __shared__ float scoefp[8][32];
    __shared__ float sw[128], sb[128];
    __shared__ float sdist[128];
    __shared__ float sxd[128][3];
    __shared__ int ssrc[128];
    __shared__ int sdst[128];

    const int t = threadIdx.x;
    const int e0 = blockIdx.x * 128;

    if (t < 128) {
        const int eid = elist[e0 + t];
        const int s = src[eid], d = dst[eid];
        ssrc[t] = s; sdst[t] = d;
        const float dx = coord[3 * s + 0] - coord[3 * d + 0];
        const float dy = coord[3 * s + 1] - coord[3 * d + 1];
        const float dz = coord[3 * s + 2] - coord[3 * d + 2];
        const float dist = sqrtf(dx * dx + dy * dy + dz * dz);
        sdist[t] = dist;
        const float inv = __fdividef(1.0f, dist + 1e-7f);
        sxd[t][0] = dx * inv; sxd[t][1] = dy * inv; sxd[t][2] = dz * inv;
    } else if (t < 160) {
        ((float4*)sw)[t - 128] = ((const float4*)(We1 + 256 * 128))[t - 128];
    } else if (t < 192) {
        ((float4*)sb)[t - 160] = ((const float4*)be1)[t - 160];
    }
    __syncthreads();

    // t1 = silu(P1[s] + P2[d] + dist*We1[256] + be1): thread = 32 cols of 1 edge
    {
        const int e = t >> 2;
        const int kc = (t & 3) * 32;
        const int s = ssrc[e], d = sdst[e];
        const float dist = sdist[e];
        const unsigned short* p1 = Pc + (size_t)s * 256 + kc;
        const unsigned short* p2 = Pc + (size_t)d * 256 + 128 + kc;
        short8 a[4], b[4];
#pragma unroll
        for (int i = 0; i < 4; i++) {
            a[i] = *(const short8*)(p1 + i * 8);
            b[i] = *(const short8*)(p2 + i * 8);
        }
#pragma unroll
        for (int i = 0; i < 4; i++) {
            float v[8];
#pragma unroll
            for (int kk = 0; kk < 8; kk++) {
                const int k = kc + i * 8 + kk;
                v[kk] = silu(bf2f((unsigned short)a[i][kk]) + bf2f((unsigned short)b[i][kk])
                             + dist * sw[k] + sb[k]);
            }
            int4 o;
            o.x = pk2bf(v[0], v[1]); o.y = pk2bf(v[2], v[3]);
            o.z = pk2bf(v[4], v[5]); o.w = pk2bf(v[6], v[7]);
            *(int4*)&sT[e][kc + i * 8] = o;
        }
    }
    __syncthreads();

    const int w = t >> 6;
    const int l = t & 63;
    const int h = w & 3;       // 32-edge group
    const int H = w >> 2;      // col half
    const int m0 = h * 32;
    const int n0 = H * 64;
    const int c = l & 15;
    const int quad = l >> 4;

    // ---- GEMM1 K-loop: acc = t1 @ We2 (M=32/wave, N=64) ----
    f32x4 acc1[2][4];
#pragma unroll
    for (int mt = 0; mt < 2; mt++)
#pragma unroll
        for (int tile = 0; tile < 4; tile++) acc1[mt][tile] = (f32x4){0.f, 0.f, 0.f, 0.f};
#pragma unroll
    for (int k0 = 0; k0 < 128; k0 += 32) {
        const short8 a0 = *(const short8*)&sT[m0 + c][k0 + quad * 8];
        const short8 a1 = *(const short8*)&sT[m0 + 16 + c][k0 + quad * 8];
#pragma unroll
        for (int tile = 0; tile < 4; tile++) {
            const short8 b = *(const short8*)(Wt_e2 +
                ((size_t)(n0 + tile * 16 + c) << 7) + k0 + quad * 8);
            acc1[0][tile] = __builtin_amdgcn_mfma_f32_16x16x32_bf16(a0, b, acc1[0][tile], 0, 0, 0);
            acc1[1][tile] = __builtin_amdgcn_mfma_f32_16x16x32_bf16(a1, b, acc1[1][tile], 0, 0, 0);
        }
    }
    __syncthreads();   // ALL waves done reading t1 before overwrite

    // ---- epilogue: t2 = silu(acc + be2) written IN PLACE over t1 ----
#pragma unroll
    for (int mt = 0; mt < 2; mt++)
#pragma unroll
        for (int tile = 0; tile < 4; tile++) {
            const int col = n0 + tile * 16 + c;
            const float bb = be2[col];
            const unsigned p01 = pk2bf(silu(acc1[mt][tile][0] + bb), silu(acc1[mt][tile][1] + bb));
            const unsigned p23 = pk2bf(silu(acc1[mt][tile][2] + bb), silu(acc1[mt][tile][3] + bb));
            const int row = m0 + mt * 16 + quad * 4;
            sT[row + 0][col] = (unsigned short)p01;
            sT[row + 1][col] = (unsigned short)(p01 >> 16);
            sT[row + 2][col] = (unsigned short)p23;
            sT[row + 3][col] = (unsigned short)(p23 >> 16);
        }
    __syncthreads();

    // ---- h-scatter first: atomics drain under GEMM2's compute ----
    {
        const int j = t & 127;
        const int q = t >> 7;
        const int eb = q * 32;
        float acc = bf2f(sT[eb][j]);
        int prev = sdst[eb];
        for (int e2 = eb + 1; e2 < eb + 32; e2++) {
            const int de = sdst[e2];
            if (de != prev) {
                atomicAdd(&h_neigh[(size_t)prev * 128 + j], acc);
                acc = 0.0f;
                prev = de;
            }
            acc += bf2f(sT[e2][j]);
        }
        atomicAdd(&h_neigh[(size_t)prev * 128 + j], acc);
    }

    // ---- GEMM2: coef = silu(t2 @ Wc1 + bc1) . Wc2 ----
    {
        f32x4 acc[2][4];
#pragma unroll
        for (int mt = 0; mt < 2; mt++)
#pragma unroll
            for (int tile = 0; tile < 4; tile++) acc[mt][tile] = (f32x4){0.f, 0.f, 0.f, 0.f};
#pragma unroll
        for (int k0 = 0; k0 < 128; k0 += 32) {
            const short8 a0 = *(const short8*)&sT[m0 + c][k0 + quad * 8];
            const short8 a1 = *(const short8*)&sT[m0 + 16 + c][k0 + quad * 8];
#pragma unroll
            for (int tile = 0; tile < 4; tile++) {
                const short8 b = *(const short8*)(Wt_c1 +
                    ((size_t)(n0 + tile * 16 + c) << 7) + k0 + quad * 8);
                acc[0][tile] = __builtin_amdgcn_mfma_f32_16x16x32_bf16(a0, b, acc[0][tile], 0, 0, 0);
                acc[1][tile] = __builtin_amdgcn_mfma_f32_16x16x32_bf16(a1, b, acc[1][tile], 0, 0, 0);
            }
        }
        float part[2][4] = {{0.f, 0.f, 0.f, 0.f}, {0.f, 0.f, 0.f, 0.f}};
#pragma unroll
        for (int tile = 0; tile < 4; tile++) {
            const int col = n0 + tile * 16 + c;
            const float bc = bc1[col];
            const float wc = Wc2[col];
#pragma unroll
            for (int mt = 0; mt < 2; mt++)
#pragma unroll
                for (int r = 0; r < 4; r++)
                    part[mt][r] += silu(acc[mt][tile][r] + bc) * wc;
        }
#pragma unroll
        for (int off = 1; off < 16; off <<= 1) {
#pragma unroll
            for (int mt = 0; mt < 2; mt++)
#pragma unroll
                for (int r = 0; r < 4; r++)
                    part[mt][r] += __shfl_xor(part[mt][r], off, 64);
        }
        if (c == 0) {
#pragma unroll
            for (int mt = 0; mt < 2; mt++)
#pragma unroll
                for (int r = 0; r < 4; r++)
                    scoefp[w][mt * 16 + quad * 4 + r] = part[mt][r];
        }
    }
    __syncthreads();

    // ---- x-scatter (12 threads; coef = colhalf0 + colhalf1 partials) ----
    if (t < 12) {
        const int q = t / 3, cc = t - q * 3;   // q = 32-edge group
        const int eb = q * 32;
        float coef = scoefp[q][0] + scoefp[q + 4][0];
        float acc = coef * sxd[eb][cc];
        int prev = sdst[eb];
        for (int e2 = eb + 1; e2 < eb + 32; e2++) {
            const int de = sdst[e2];
            if (de != prev) {
                atomicAdd(&xs[(size_t)prev * 4 + cc], acc);
                acc = 0.0f;
                prev = de;
            }
            coef = scoefp[q][e2 & 31] + scoefp[q + 4][e2 & 31];
            acc += coef * sxd[e2][cc];
        }
        atomicAdd(&xs[(size_t)prev * 4 + cc], acc);
    }
}

// ---------------------------------------------------------------------------
// k_node (MFMA): h = silu([nf|hn] @ Wn1 + bn1) @ Wn2 + bn2 ; x = coord+xs/cnt
// ---------------------------------------------------------------------------
__global__ __launch_bounds__(256) void k_node(
    const float* __restrict__ nf, const float* __restrict__ coord,
    const float* __restrict__ hn, const float* __restrict__ xs,
    const int* __restrict__ row_start,
    const unsigned short* __restrict__ Wt_n1, const float* __restrict__ bn1,
    const unsigned short* __restrict__ Wt_n2, const float* __restrict__ bn2,
    float* __restrict__ out_h, float* __restrict__ out_x) {
    __shared__ __align__(16) unsigned short sAB[32][264];
    __shared__ __align__(16) unsigned short sH[32][136];
    const int t = threadIdx.x;
    const int node0 = blockIdx.x * 32;
    {
        const int m = t >> 3, kc = (t & 7) * 32;
        const float* base = (kc < 128) ? &nf[(size_t)(node0 + m) * 128 + kc]
                                       : &hn[(size_t)(node0 + m) * 128 + (kc - 128)];
#pragma unroll
        for (int kk = 0; kk < 32; kk += 8) {
            const float4 v0 = *(const float4*)(base + kk);
            const float4 v1 = *(const float4*)(base + kk + 4);
            int4 o;
            o.x = pk2bf(v0.x, v0.y); o.y = pk2bf(v0.z, v0.w);
            o.z = pk2bf(v1.x, v1.y); o.w = pk2bf(v1.z, v1.w);
            *(int4*)&sAB[m][kc + kk] = o;
        }
    }
    if (t < 96) {
        const int m = t / 3, cc = t - m * 3;
        const int i = node0 + m;
        const float cnt = (float)(row_start[i + 1] - row_start[i]);
        out_x[(size_t)i * 3 + cc] =
            coord[(size_t)i * 3 + cc] + __fdividef(xs[(size_t)i * 4 + cc], fmaxf(cnt, 1.0f));
    }
    __syncthreads();

    const int w = t >> 6, l = t & 63, c = l & 15, quad = l >> 4;
    const int n0 = w * 32;

    // GEMM1: M=32, K=256, N=128
    {
        f32x4 acc[2][2];
#pragma unroll
        for (int mt = 0; mt < 2; mt++)
#pragma unroll
            for (int tile = 0; tile < 2; tile++) acc[mt][tile] = (f32x4){0.f, 0.f, 0.f, 0.f};
#pragma unroll
        for (int k0 = 0; k0 < 256; k0 += 32) {
            const short8 a0 = *(const short8*)&sAB[c][k0 + quad * 8];
            const short8 a1 = *(const short8*)&sAB[16 + c][k0 + quad * 8];
#pragma unroll
            for (int tile = 0; tile < 2; tile++) {
                const short8 b = *(const short8*)(Wt_n1 +
                    ((size_t)(n0 + tile * 16 + c) << 8) + k0 + quad * 8);
                acc[0][tile] = __builtin_amdgcn_mfma_f32_16x16x32_bf16(a0, b, acc[0][tile], 0, 0, 0);
                acc[1][tile] = __builtin_amdgcn_mfma_f32_16x16x32_bf16(a1, b, acc[1][tile], 0, 0, 0);
            }
        }
#pragma unroll
        for (int mt = 0; mt < 2; mt++)
#pragma unroll
            for (int tile = 0; tile < 2; tile++) {
                const int col = n0 + tile * 16 + c;
                const float bb = bn1[col];
                const unsigned p01 = pk2bf(silu(acc[mt][tile][0] + bb), silu(acc[mt][tile][1] + bb));
                const unsigned p23 = pk2bf(silu(acc[mt][tile][2] + bb), silu(acc[mt][tile][3] + bb));
                const int row = mt * 16 + quad * 4;
                sH[row + 0][col] = (unsigned short)p01;
                sH[row + 1][col] = (unsigned short)(p01 >> 16);
                sH[row + 2][col] = (unsigned short)p23;
                sH[row + 3][col] = (unsigned short)(p23 >> 16);
            }
    }
    __syncthreads();

    // GEMM2: M=32, K=128, N=128
    {
        f32x4 acc[2][2];
#pragma unroll
        for (int mt = 0; mt < 2; mt++)
#pragma unroll
            for (int tile = 0; tile < 2; tile++) acc[mt][tile] = (f32x4){0.f, 0.f, 0.f, 0.f};
#pragma unroll
        for (int k0 = 0; k0 < 128; k0 += 32) {
            const short8 a0 = *(const short8*)&sH[c][k0 + quad * 8];
            const short8 a1 = *(const short8*)&sH[16 + c][k0 + quad * 8];
#pragma unroll
            for (int tile = 0; tile < 2; tile++) {
                const short8 b = *(const short8*)(Wt_n2 +
                    ((size_t)(n0 + tile * 16 + c) << 7) + k0 + quad * 8);
                acc[0][tile] = __builtin_amdgcn_mfma_f32_16x16x32_bf16(a0, b, acc[0][tile], 0, 0, 0);
                acc[1][tile] = __builtin_amdgcn_mfma_f32_16x16x32_bf16(a1, b, acc[1][tile], 0, 0, 0);
            }
        }
#pragma unroll
        for (int mt = 0; mt < 2; mt++)
#pragma unroll
            for (int tile = 0; tile < 2; tile++) {
                const int col = n0 + tile * 16 + c;
                const float bb = bn2[col];
#pragma unroll
                for (int r = 0; r < 4; r++) {
                    const int row = mt * 16 + quad * 4 + r;
                    out_h[(size_t)(node0 + row) * 128 + col] = acc[mt][tile][r] + bb;
                }
            }
    }
}

// ---------------------------------------------------------------------------
extern "C" void kernel_launch(void* const* d_in, const int* in_sizes, int n_in,
                              void* d_out, int out_size, void* d_ws, size_t ws_size,
                              hipStream_t stream) {
    const float* nf    = (const float*)d_in[0];
    const float* coord = (const float*)d_in[1];
    const int*   src   = (const int*)d_in[2];
    const int*   dst   = (const int*)d_in[3];
    const float* We1   = (const float*)d_in[4];
    const float* be1   = (const float*)d_in[5];
    const float* We2   = (const float*)d_in[6];
    const float* be2   = (const float*)d_in[7];
    const float* Wn1   = (const float*)d_in[8];
    const float* bn1   = (const float*)d_in[9];
    const float* Wn2   = (const float*)d_in[10];
    const float* bn2   = (const float*)d_in[11];
    const float* Wc1   = (const float*)d_in[12];
    const float* bc1   = (const float*)d_in[13];
    const float* Wc2   = (const float*)d_in[14];

    unsigned short* Pc = (unsigned short*)d_ws;            // N*256 bf16
    float* hn = (float*)(Pc + (size_t)N_NODES * 256);      // N*128 f32
    float* xs = hn + (size_t)N_NODES * 128;                // N*4
    int* deg       = (int*)(xs + (size_t)N_NODES * 4);     // N
    int* row_start = deg + N_NODES;                        // N+1
    int* cursor    = row_start + N_NODES + 1;              // N
    int* elist     = cursor + N_NODES;                     // E
    unsigned short* Wt_e1 = (unsigned short*)
        (((uintptr_t)(elist + N_EDGES) + 255) & ~(uintptr_t)255);  // 256*128
    unsigned short* Wt_e2 = Wt_e1 + 256 * 128;                     // 128*128
    unsigned short* Wt_c1 = Wt_e2 + 128 * 128;                     // 128*128
    unsigned short* Wt_n1 = Wt_c1 + 128 * 128;                     // 128*256
    unsigned short* Wt_n2 = Wt_n1 + 128 * 256;                     // 128*128

    float* out_h = (float*)d_out;                          // N*128
    float* out_x = out_h + (size_t)N_NODES * 128;          // N*3

    k_pack2<<<256, 128, 0, stream>>>(We1, We2, Wc1, Wn1, Wn2,
                                     Wt_e1, Wt_e2, Wt_c1, Wt_n1, Wt_n2,
                                     deg, cursor, xs, hn);
    k_count<<<(N_EDGES + 255) / 256, 256, 0, stream>>>(dst, deg);
    k_scan<<<1, 1024, 0, stream>>>(deg, row_start);
    k_fill<<<(N_EDGES + 255) / 256, 256, 0, stream>>>(dst, row_start, cursor, elist);
    k_pre<<<N_NODES / 32, 256, 0, stream>>>(nf, Wt_e1, Pc);
    k_edge5<<<N_EDGES / 128, 512, 0, stream>>>(Pc, coord, src, dst, elist,
                                               We1, be1, Wt_e2, be2, Wt_c1, bc1,
                                               Wc2, hn, xs);
    k_node<<<N_NODES / 32, 256, 0, stream>>>(nf, coord, hn, xs, row_start,
                                             Wt_n1, bn1, Wt_n2, bn2, out_h, out_x);
}

// Round 10
// 477.373 us; speedup vs baseline: 1.1791x; 1.0390x over previous
//
#include <hip/hip_runtime.h>
#include <hip/hip_bf16.h>
#include <math.h>
#include <stdint.h>

#define N_NODES 40000
#define N_EDGES 640000

typedef short short8 __attribute__((ext_vector_type(8)));
typedef float f32x4 __attribute__((ext_vector_type(4)));

__device__ __forceinline__ float silu(float x) {
    return __fdividef(x, 1.0f + __expf(-x));
}

__device__ __forceinline__ unsigned short f2bf(float f) {
    unsigned u = __float_as_uint(f);
    u += 0x7FFF + ((u >> 16) & 1);
    return (unsigned short)(u >> 16);
}
__device__ __forceinline__ float bf2f(unsigned short h) {
    return __uint_as_float(((unsigned)h) << 16);
}
__device__ __forceinline__ unsigned pk2bf(float a, float b) {
    __hip_bfloat162 h = __float22bfloat162_rn(make_float2(a, b));
    unsigned u;
    __builtin_memcpy(&u, &h, 4);
    return u;
}

// ---------------------------------------------------------------------------
// k_scan: shuffle-based hierarchical exclusive scan of deg -> row_start.
// ---------------------------------------------------------------------------
__global__ __launch_bounds__(1024) void k_scan(const int* __restrict__ deg,
                                               int* __restrict__ row_start) {
    __shared__ int wsum[16];
    const int t = threadIdx.x;
    const int lane = t & 63, wid = t >> 6;
    int base = 0;
    if (t == 0) row_start[0] = 0;
    for (int off = 0; off < N_NODES; off += 1024) {
        int x = (off + t < N_NODES) ? deg[off + t] : 0;
#pragma unroll
        for (int s = 1; s < 64; s <<= 1) {
            const int u = __shfl_up(x, s, 64);
            if (lane >= s) x += u;
        }
        if (lane == 63) wsum[wid] = x;
        __syncthreads();
        if (wid == 0) {
            int ws = (lane < 16) ? wsum[lane] : 0;
#pragma unroll
            for (int s = 1; s < 16; s <<= 1) {
                const int u = __shfl_up(ws, s, 64);
                if (lane >= s) ws += u;
            }
            if (lane < 16) wsum[lane] = ws;
        }
        __syncthreads();
        const int wbase = (wid > 0) ? wsum[wid - 1] : 0;
        const int total = wsum[15];
        if (off + t < N_NODES) row_start[off + t + 1] = base + wbase + x;
        base += total;
        __syncthreads();
    }
}

__global__ __launch_bounds__(256) void k_fill(const int* __restrict__ dst,
                                              const int* __restrict__ row_start,
                                              int* __restrict__ cursor,
                                              int* __restrict__ elist) {
    const int e = blockIdx.x * 256 + threadIdx.x;
    if (e < N_EDGES) {
        const int d = dst[e];
        const int p = atomicAdd(&cursor[d], 1);
        elist[row_start[d] + p] = e;
    }
}

// ---------------------------------------------------------------------------
// k_pack2: bf16-transposed weight packs + folded memsets (deg/cursor/xs/hn).
// ---------------------------------------------------------------------------
__global__ __launch_bounds__(128) void k_pack2(
    const float* __restrict__ We1, const float* __restrict__ We2,
    const float* __restrict__ Wc1, const float* __restrict__ Wn1,
    const float* __restrict__ Wn2,
    unsigned short* __restrict__ Wt_e1, unsigned short* __restrict__ Wt_e2,
    unsigned short* __restrict__ Wt_c1, unsigned short* __restrict__ Wt_n1,
    unsigned short* __restrict__ Wt_n2,
    int* __restrict__ deg, int* __restrict__ cursor, float* __restrict__ xs,
    float* __restrict__ hn) {
    const int b = blockIdx.x;   // 0..255
    const int t = threadIdx.x;  // 0..127
    Wt_e1[b * 128 + t] = f2bf(We1[(size_t)((b >> 7) * 128 + t) * 128 + (b & 127)]);
    if (b < 128) {
        Wt_e2[b * 128 + t] = f2bf(We2[(size_t)t * 128 + b]);
        Wt_c1[b * 128 + t] = f2bf(Wc1[(size_t)t * 128 + b]);
        Wt_n2[b * 128 + t] = f2bf(Wn2[(size_t)t * 128 + b]);
        Wt_n1[b * 256 + t] = f2bf(Wn1[(size_t)t * 128 + b]);
        Wt_n1[b * 256 + 128 + t] = f2bf(Wn1[(size_t)(128 + t) * 128 + b]);
    }
    const int gid = b * 128 + t;                   // 0..32767
    for (int i = gid; i < N_NODES; i += 32768) { deg[i] = 0; cursor[i] = 0; }
    for (int i = gid; i < N_NODES * 4; i += 32768) xs[i] = 0.0f;
    float4* hz = (float4*)hn;
    const float4 z4 = {0.f, 0.f, 0.f, 0.f};
    for (int i = gid; i < N_NODES * 32; i += 32768) hz[i] = z4;
}

// ---------------------------------------------------------------------------
// k_cntpre: dst-degree histogram (2 edges/thread; atomics drain under MFMA)
// fused with k_pre (MFMA): Pc[node][0:256] = nf @ [We1a|We1b], bf16 out.
// 1250 blocks x 256 threads; 1250*256*2 == N_EDGES exactly.
// ---------------------------------------------------------------------------
__global__ __launch_bounds__(256) void k_cntpre(
    const float* __restrict__ nf, const unsigned short* __restrict__ Wt_e1,
    unsigned short* __restrict__ Pc,
    const int* __restrict__ dst, int* __restrict__ deg) {
    __shared__ __align__(16) unsigned short sNF[32][136];
    const int t = threadIdx.x;
    const int node0 = blockIdx.x * 32;
    {
        const int e0 = (blockIdx.x * 256 + t) * 2;
        const int d0 = dst[e0], d1 = dst[e0 + 1];
        atomicAdd(&deg[d0], 1);
        atomicAdd(&deg[d1], 1);
    }
    {
        const int m = t >> 3, kc = (t & 7) * 16;
        const float* sp = &nf[(size_t)(node0 + m) * 128 + kc];
        const float4 v0 = *(const float4*)(sp + 0);
        const float4 v1 = *(const float4*)(sp + 4);
        const float4 v2 = *(const float4*)(sp + 8);
        const float4 v3 = *(const float4*)(sp + 12);
        int4 o0, o1;
        o0.x = pk2bf(v0.x, v0.y); o0.y = pk2bf(v0.z, v0.w);
        o0.z = pk2bf(v1.x, v1.y); o0.w = pk2bf(v1.z, v1.w);
        o1.x = pk2bf(v2.x, v2.y); o1.y = pk2bf(v2.z, v2.w);
        o1.z = pk2bf(v3.x, v3.y); o1.w = pk2bf(v3.z, v3.w);
        *(int4*)&sNF[m][kc] = o0;
        *(int4*)&sNF[m][kc + 8] = o1;
    }
    __syncthreads();

    const int w = t >> 6, l = t & 63, c = l & 15, quad = l >> 4;
    const int n0 = w * 64;

    f32x4 acc[2][4];
#pragma unroll
    for (int mt = 0; mt < 2; mt++)
#pragma unroll
        for (int tile = 0; tile < 4; tile++) acc[mt][tile] = (f32x4){0.f, 0.f, 0.f, 0.f};

#pragma unroll
    for (int k0 = 0; k0 < 128; k0 += 32) {
        const short8 a0 = *(const short8*)&sNF[c][k0 + quad * 8];
        const short8 a1 = *(const short8*)&sNF[16 + c][k0 + quad * 8];
#pragma unroll
        for (int tile = 0; tile < 4; tile++) {
            const short8 b = *(const short8*)(Wt_e1 +
                ((size_t)(n0 + tile * 16 + c) << 7) + k0 + quad * 8);
            acc[0][tile] = __builtin_amdgcn_mfma_f32_16x16x32_bf16(a0, b, acc[0][tile], 0, 0, 0);
            acc[1][tile] = __builtin_amdgcn_mfma_f32_16x16x32_bf16(a1, b, acc[1][tile], 0, 0, 0);
        }
    }
#pragma unroll
    for (int mt = 0; mt < 2; mt++)
#pragma unroll
        for (int tile = 0; tile < 4; tile++) {
            const int col = n0 + tile * 16 + c;
            const unsigned p01 = pk2bf(acc[mt][tile][0], acc[mt][tile][1]);
            const unsigned p23 = pk2bf(acc[mt][tile][2], acc[mt][tile][3]);
            const int row = node0 + mt * 16 + quad * 4;
            Pc[(size_t)(row + 0) * 256 + col] = (unsigned short)p01;
            Pc[(size_t)(row + 1) * 256 + col] = (unsigned short)(p01 >> 16);
            Pc[(size_t)(row + 2) * 256 + col] = (unsigned short)p23;
            Pc[(size_t)(row + 3) * 256 + col] = (unsigned short)(p23 >> 16);
        }
}

// ---------------------------------------------------------------------------
// k_edge5: 128 CSR-permuted edges per 512-thread block (8 waves), 4 barriers.
//   Single LDS tile sT reused (t1 -> t2 in place). x-scatter is wave-local
//   with PARTIAL coefs (each col-half wave scatters its partial; atomics sum).
// ---------------------------------------------------------------------------
__global__ __launch_bounds__(512) void k_edge5(
    const unsigned short* __restrict__ Pc, const float* __restrict__ coord,
    const int* __restrict__ src, const int* __restrict__ dst,
    const int* __restrict__ elist,
    const float* __restrict__ We1, const float* __restrict__ be1,
    const unsigned short* __restrict__ Wt_e2, const float* __restrict__ be2,
    const unsigned short* __restrict__ Wt_c1, const float* __restrict__ bc1,
    const float* __restrict__ Wc2,
    float* __restrict__ h_neigh, float* __restrict__ xs) {
    __shared__ __align__(16) unsigned short sT[128][136];
    __shared__ float scoefp[8][32];          // wave-private rows
    __shared__ float sw[128], sb[128];
    __shared__ float sdist[128];
    __shared__ float sxd[128][3];
    __shared__ int ssrc[128];
    __shared__ int sdst[128];

    const int t = threadIdx.x;
    const int e0 = blockIdx.x * 128;

    if (t < 128) {
        const int eid = elist[e0 + t];
        const int s = src[eid], d = dst[eid];
        ssrc[t] = s; sdst[t] = d;
        const float dx = coord[3 * s + 0] - coord[3 * d + 0];
        const float dy = coord[3 * s + 1] - coord[3 * d + 1];
        const float dz = coord[3 * s + 2] - coord[3 * d + 2];
        const float dist = sqrtf(dx * dx + dy * dy + dz * dz);
        sdist[t] = dist;
        const float inv = __fdividef(1.0f, dist + 1e-7f);
        sxd[t][0] = dx * inv; sxd[t][1] = dy * inv; sxd[t][2] = dz * inv;
    } else if (t < 160) {
        ((float4*)sw)[t - 128] = ((const float4*)(We1 + 256 * 128))[t - 128];
    } else if (t < 192) {
        ((float4*)sb)[t - 160] = ((const float4*)be1)[t - 160];
    }
    __syncthreads();

    // t1 = silu(P1[s] + P2[d] + dist*We1[256] + be1): thread = 32 cols of 1 edge
    {
        const int e = t >> 2;
        const int kc = (t & 3) * 32;
        const int s = ssrc[e], d = sdst[e];
        const float dist = sdist[e];
        const unsigned short* p1 = Pc + (size_t)s * 256 + kc;
        const unsigned short* p2 = Pc + (size_t)d * 256 + 128 + kc;
        short8 a[4], b[4];
#pragma unroll
        for (int i = 0; i < 4; i++) {
            a[i] = *(const short8*)(p1 + i * 8);
            b[i] = *(const short8*)(p2 + i * 8);
        }
#pragma unroll
        for (int i = 0; i < 4; i++) {
            float v[8];
#pragma unroll
            for (int kk = 0; kk < 8; kk++) {
                const int k = kc + i * 8 + kk;
                v[kk] = silu(bf2f((unsigned short)a[i][kk]) + bf2f((unsigned short)b[i][kk])
                             + dist * sw[k] + sb[k]);
            }
            int4 o;
            o.x = pk2bf(v[0], v[1]); o.y = pk2bf(v[2], v[3]);
            o.z = pk2bf(v[4], v[5]); o.w = pk2bf(v[6], v[7]);
            *(int4*)&sT[e][kc + i * 8] = o;
        }
    }
    __syncthreads();

    const int w = t >> 6;
    const int l = t & 63;
    const int h = w & 3;       // 32-edge group
    const int H = w >> 2;      // col half
    const int m0 = h * 32;
    const int n0 = H * 64;
    const int c = l & 15;
    const int quad = l >> 4;

    // ---- GEMM1 K-loop: acc = t1 @ We2 (M=32/wave, N=64) ----
    f32x4 acc1[2][4];
#pragma unroll
    for (int mt = 0; mt < 2; mt++)
#pragma unroll
        for (int tile = 0; tile < 4; tile++) acc1[mt][tile] = (f32x4){0.f, 0.f, 0.f, 0.f};
#pragma unroll
    for (int k0 = 0; k0 < 128; k0 += 32) {
        const short8 a0 = *(const short8*)&sT[m0 + c][k0 + quad * 8];
        const short8 a1 = *(const short8*)&sT[m0 + 16 + c][k0 + quad * 8];
#pragma unroll
        for (int tile = 0; tile < 4; tile++) {
            const short8 b = *(const short8*)(Wt_e2 +
                ((size_t)(n0 + tile * 16 + c) << 7) + k0 + quad * 8);
            acc1[0][tile] = __builtin_amdgcn_mfma_f32_16x16x32_bf16(a0, b, acc1[0][tile], 0, 0, 0);
            acc1[1][tile] = __builtin_amdgcn_mfma_f32_16x16x32_bf16(a1, b, acc1[1][tile], 0, 0, 0);
        }
    }
    __syncthreads();   // ALL waves done reading t1 before overwrite

    // ---- epilogue: t2 = silu(acc + be2) written IN PLACE over t1 ----
#pragma unroll
    for (int mt = 0; mt < 2; mt++)
#pragma unroll
        for (int tile = 0; tile < 4; tile++) {
            const int col = n0 + tile * 16 + c;
            const float bb = be2[col];
            const unsigned p01 = pk2bf(silu(acc1[mt][tile][0] + bb), silu(acc1[mt][tile][1] + bb));
            const unsigned p23 = pk2bf(silu(acc1[mt][tile][2] + bb), silu(acc1[mt][tile][3] + bb));
            const int row = m0 + mt * 16 + quad * 4;
            sT[row + 0][col] = (unsigned short)p01;
            sT[row + 1][col] = (unsigned short)(p01 >> 16);
            sT[row + 2][col] = (unsigned short)p23;
            sT[row + 3][col] = (unsigned short)(p23 >> 16);
        }
    __syncthreads();

    // ---- h-scatter first: atomics drain under GEMM2's compute ----
    {
        const int j = t & 127;
        const int q = t >> 7;
        const int eb = q * 32;
        float acc = bf2f(sT[eb][j]);
        int prev = sdst[eb];
        for (int e2 = eb + 1; e2 < eb + 32; e2++) {
            const int de = sdst[e2];
            if (de != prev) {
                atomicAdd(&h_neigh[(size_t)prev * 128 + j], acc);
                acc = 0.0f;
                prev = de;
            }
            acc += bf2f(sT[e2][j]);
        }
        atomicAdd(&h_neigh[(size_t)prev * 128 + j], acc);
    }

    // ---- GEMM2: coef = silu(t2 @ Wc1 + bc1) . Wc2 ----
    {
        f32x4 acc[2][4];
#pragma unroll
        for (int mt = 0; mt < 2; mt++)
#pragma unroll
            for (int tile = 0; tile < 4; tile++) acc[mt][tile] = (f32x4){0.f, 0.f, 0.f, 0.f};
#pragma unroll
        for (int k0 = 0; k0 < 128; k0 += 32) {
            const short8 a0 = *(const short8*)&sT[m0 + c][k0 + quad * 8];
            const short8 a1 = *(const short8*)&sT[m0 + 16 + c][k0 + quad * 8];
#pragma unroll
            for (int tile = 0; tile < 4; tile++) {
                const short8 b = *(const short8*)(Wt_c1 +
                    ((size_t)(n0 + tile * 16 + c) << 7) + k0 + quad * 8);
                acc[0][tile] = __builtin_amdgcn_mfma_f32_16x16x32_bf16(a0, b, acc[0][tile], 0, 0, 0);
                acc[1][tile] = __builtin_amdgcn_mfma_f32_16x16x32_bf16(a1, b, acc[1][tile], 0, 0, 0);
            }
        }
        float part[2][4] = {{0.f, 0.f, 0.f, 0.f}, {0.f, 0.f, 0.f, 0.f}};
#pragma unroll
        for (int tile = 0; tile < 4; tile++) {
            const int col = n0 + tile * 16 + c;
            const float bc = bc1[col];
            const float wc = Wc2[col];
#pragma unroll
            for (int mt = 0; mt < 2; mt++)
#pragma unroll
                for (int r = 0; r < 4; r++)
                    part[mt][r] += silu(acc[mt][tile][r] + bc) * wc;
        }
#pragma unroll
        for (int off = 1; off < 16; off <<= 1) {
#pragma unroll
            for (int mt = 0; mt < 2; mt++)
#pragma unroll
                for (int r = 0; r < 4; r++)
                    part[mt][r] += __shfl_xor(part[mt][r], off, 64);
        }
        if (c == 0) {
#pragma unroll
            for (int mt = 0; mt < 2; mt++)
#pragma unroll
                for (int r = 0; r < 4; r++)
                    scoefp[w][mt * 16 + quad * 4 + r] = part[mt][r];
        }
    }

    // ---- x-scatter: wave-local, partial coefs (no barrier; atomics sum the
    //      two col-half partials). 3 lanes per wave iterate this wave's
    //      32-edge group; scoefp[w] written above by the SAME wave. ----
    if (l < 3) {
        const int cc = l;
        const int eb = h * 32;
        float acc = scoefp[w][0] * sxd[eb][cc];
        int prev = sdst[eb];
        for (int e2 = eb + 1; e2 < eb + 32; e2++) {
            const int de = sdst[e2];
            if (de != prev) {
                atomicAdd(&xs[(size_t)prev * 4 + cc], acc);
                acc = 0.0f;
                prev = de;
            }
            acc += scoefp[w][e2 & 31] * sxd[e2][cc];
        }
        atomicAdd(&xs[(size_t)prev * 4 + cc], acc);
    }
}

// ---------------------------------------------------------------------------
// k_node (MFMA): h = silu([nf|hn] @ Wn1 + bn1) @ Wn2 + bn2 ; x = coord+xs/cnt
// ---------------------------------------------------------------------------
__global__ __launch_bounds__(256) void k_node(
    const float* __restrict__ nf, const float* __restrict__ coord,
    const float* __restrict__ hn, const float* __restrict__ xs,
    const int* __restrict__ row_start,
    const unsigned short* __restrict__ Wt_n1, const float* __restrict__ bn1,
    const unsigned short* __restrict__ Wt_n2, const float* __restrict__ bn2,
    float* __restrict__ out_h, float* __restrict__ out_x) {
    __shared__ __align__(16) unsigned short sAB[32][264];
    __shared__ __align__(16) unsigned short sH[32][136];
    const int t = threadIdx.x;
    const int node0 = blockIdx.x * 32;
    {
        const int m = t >> 3, kc = (t & 7) * 32;
        const float* base = (kc < 128) ? &nf[(size_t)(node0 + m) * 128 + kc]
                                       : &hn[(size_t)(node0 + m) * 128 + (kc - 128)];
#pragma unroll
        for (int kk = 0; kk < 32; kk += 8) {
            const float4 v0 = *(const float4*)(base + kk);
            const float4 v1 = *(const float4*)(base + kk + 4);
            int4 o;
            o.x = pk2bf(v0.x, v0.y); o.y = pk2bf(v0.z, v0.w);
            o.z = pk2bf(v1.x, v1.y); o.w = pk2bf(v1.z, v1.w);
            *(int4*)&sAB[m][kc + kk] = o;
        }
    }
    if (t < 96) {
        const int m = t / 3, cc = t - m * 3;
        const int i = node0 + m;
        const float cnt = (float)(row_start[i + 1] - row_start[i]);
        out_x[(size_t)i * 3 + cc] =
            coord[(size_t)i * 3 + cc] + __fdividef(xs[(size_t)i * 4 + cc], fmaxf(cnt, 1.0f));
    }
    __syncthreads();

    const int w = t >> 6, l = t & 63, c = l & 15, quad = l >> 4;
    const int n0 = w * 32;

    // GEMM1: M=32, K=256, N=128
    {
        f32x4 acc[2][2];
#pragma unroll
        for (int mt = 0; mt < 2; mt++)
#pragma unroll
            for (int tile = 0; tile < 2; tile++) acc[mt][tile] = (f32x4){0.f, 0.f, 0.f, 0.f};
#pragma unroll
        for (int k0 = 0; k0 < 256; k0 += 32) {
            const short8 a0 = *(const short8*)&sAB[c][k0 + quad * 8];
            const short8 a1 = *(const short8*)&sAB[16 + c][k0 + quad * 8];
#pragma unroll
            for (int tile = 0; tile < 2; tile++) {
                const short8 b = *(const short8*)(Wt_n1 +
                    ((size_t)(n0 + tile * 16 + c) << 8) + k0 + quad * 8);
                acc[0][tile] = __builtin_amdgcn_mfma_f32_16x16x32_bf16(a0, b, acc[0][tile], 0, 0, 0);
                acc[1][tile] = __builtin_amdgcn_mfma_f32_16x16x32_bf16(a1, b, acc[1][tile], 0, 0, 0);
            }
        }
#pragma unroll
        for (int mt = 0; mt < 2; mt++)
#pragma unroll
            for (int tile = 0; tile < 2; tile++) {
                const int col = n0 + tile * 16 + c;
                const float bb = bn1[col];
                const unsigned p01 = pk2bf(silu(acc[mt][tile][0] + bb), silu(acc[mt][tile][1] + bb));
                const unsigned p23 = pk2bf(silu(acc[mt][tile][2] + bb), silu(acc[mt][tile][3] + bb));
                const int row = mt * 16 + quad * 4;
                sH[row + 0][col] = (unsigned short)p01;
                sH[row + 1][col] = (unsigned short)(p01 >> 16);
                sH[row + 2][col] = (unsigned short)p23;
                sH[row + 3][col] = (unsigned short)(p23 >> 16);
            }
    }
    __syncthreads();

    // GEMM2: M=32, K=128, N=128
    {
        f32x4 acc[2][2];
#pragma unroll
        for (int mt = 0; mt < 2; mt++)
#pragma unroll
            for (int tile = 0; tile < 2; tile++) acc[mt][tile] = (f32x4){0.f, 0.f, 0.f, 0.f};
#pragma unroll
        for (int k0 = 0; k0 < 128; k0 += 32) {
            const short8 a0 = *(const short8*)&sH[c][k0 + quad * 8];
            const short8 a1 = *(const short8*)&sH[16 + c][k0 + quad * 8];
#pragma unroll
            for (int tile = 0; tile < 2; tile++) {
                const short8 b = *(const short8*)(Wt_n2 +
                    ((size_t)(n0 + tile * 16 + c) << 7) + k0 + quad * 8);
                acc[0][tile] = __builtin_amdgcn_mfma_f32_16x16x32_bf16(a0, b, acc[0][tile], 0, 0, 0);
                acc[1][tile] = __builtin_amdgcn_mfma_f32_16x16x32_bf16(a1, b, acc[1][tile], 0, 0, 0);
            }
        }
#pragma unroll
        for (int mt = 0; mt < 2; mt++)
#pragma unroll
            for (int tile = 0; tile < 2; tile++) {
                const int col = n0 + tile * 16 + c;
                const float bb = bn2[col];
#pragma unroll
                for (int r = 0; r < 4; r++) {
                    const int row = mt * 16 + quad * 4 + r;
                    out_h[(size_t)(node0 + row) * 128 + col] = acc[mt][tile][r] + bb;
                }
            }
    }
}

// ---------------------------------------------------------------------------
extern "C" void kernel_launch(void* const* d_in, const int* in_sizes, int n_in,
                              void* d_out, int out_size, void* d_ws, size_t ws_size,
                              hipStream_t stream) {
    const float* nf    = (const float*)d_in[0];
    const float* coord = (const float*)d_in[1];
    const int*   src   = (const int*)d_in[2];
    const int*   dst   = (const int*)d_in[3];
    const float* We1   = (const float*)d_in[4];
    const float* be1   = (const float*)d_in[5];
    const float* We2   = (const float*)d_in[6];
    const float* be2   = (const float*)d_in[7];
    const float* Wn1   = (const float*)d_in[8];
    const float* bn1   = (const float*)d_in[9];
    const float* Wn2   = (const float*)d_in[10];
    const float* bn2   = (const float*)d_in[11];
    const float* Wc1   = (const float*)d_in[12];
    const float* bc1   = (const float*)d_in[13];
    const float* Wc2   = (const float*)d_in[14];

    unsigned short* Pc = (unsigned short*)d_ws;            // N*256 bf16
    float* hn = (float*)(Pc + (size_t)N_NODES * 256);      // N*128 f32
    float* xs = hn + (size_t)N_NODES * 128;                // N*4
    int* deg       = (int*)(xs + (size_t)N_NODES * 4);     // N
    int* row_start = deg + N_NODES;                        // N+1
    int* cursor    = row_start + N_NODES + 1;              // N
    int* elist     = cursor + N_NODES;                     // E
    unsigned short* Wt_e1 = (unsigned short*)
        (((uintptr_t)(elist + N_EDGES) + 255) & ~(uintptr_t)255);  // 256*128
    unsigned short* Wt_e2 = Wt_e1 + 256 * 128;                     // 128*128
    unsigned short* Wt_c1 = Wt_e2 + 128 * 128;                     // 128*128
    unsigned short* Wt_n1 = Wt_c1 + 128 * 128;                     // 128*256
    unsigned short* Wt_n2 = Wt_n1 + 128 * 256;                     // 128*128

    float* out_h = (float*)d_out;                          // N*128
    float* out_x = out_h + (size_t)N_NODES * 128;          // N*3

    k_pack2<<<256, 128, 0, stream>>>(We1, We2, Wc1, Wn1, Wn2,
                                     Wt_e1, Wt_e2, Wt_c1, Wt_n1, Wt_n2,
                                     deg, cursor, xs, hn);
    k_cntpre<<<N_NODES / 32, 256, 0, stream>>>(nf, Wt_e1, Pc, dst, deg);
    k_scan<<<1, 1024, 0, stream>>>(deg, row_start);
    k_fill<<<(N_EDGES + 255) / 256, 256, 0, stream>>>(dst, row_start, cursor, elist);
    k_edge5<<<N_EDGES / 128, 512, 0, stream>>>(Pc, coord, src, dst, elist,
                                               We1, be1, Wt_e2, be2, Wt_c1, bc1,
                                               Wc2, hn, xs);
    k_node<<<N_NODES / 32, 256, 0, stream>>>(nf, coord, hn, xs, row_start,
                                             Wt_n1, bn1, Wt_n2, bn2, out_h, out_x);
}